// Round 2
// baseline (13463.310 us; speedup 1.0000x reference)
//
#include <hip/hip_runtime.h>

// Problem constants
#define DIMD   256
#define NTOK   16384
#define NCODE  8192
#define NELEM  (NTOK * DIMD)

// fp32 project-GEMM tiling (round-1 kernel, kept: it's ~10 us)
#define BM 128
#define BK 128
#define BD 32
#define PAD 4
#define LDS_STRIDE (BM + PAD)

// MFMA distance-GEMM tiling
#define GBM 128          // tokens per block
#define GBK 128          // codes per k-tile
#define KT  8            // k-tiles per block -> 1024 codes/block
#define GBD 64           // d-chunk per LDS stage
#define MARGIN 0.75f     // > 2 * worst-case bf16 distance error (~0.38)

typedef float floatx4 __attribute__((ext_vector_type(4)));
typedef short short8  __attribute__((ext_vector_type(8)));

__device__ __forceinline__ unsigned short f2bf(float f) {
    unsigned u = __float_as_uint(f);
    unsigned r = (u + 0x7FFFu + ((u >> 16) & 1u)) >> 16;
    return (unsigned short)r;
}

__device__ __forceinline__ void async_copy16(const void* g, void* l) {
    __builtin_amdgcn_global_load_lds(
        (const __attribute__((address_space(1))) unsigned int*)g,
        (__attribute__((address_space(3))) unsigned int*)l, 16, 0, 0);
}

// -------------------------------------------------------------------------
// Kernel 1: codebook projection C[k][j] = sum_i E[k][i]*W[j][i] + b[j]
// (fp32, round-1 structure) + bf16 copy Cb.
// -------------------------------------------------------------------------
__global__ __launch_bounds__(256, 3)
void project_kernel(const float* __restrict__ E, const float* __restrict__ W,
                    const float* __restrict__ bias, float* __restrict__ C,
                    unsigned short* __restrict__ Cb)
{
    __shared__ float smem[2 * BD * LDS_STRIDE];
    float* As = smem;
    float* Bs = smem + BD * LDS_STRIDE;

    const int tid = threadIdx.x;
    const int tx  = tid & 15;
    const int ty  = tid >> 4;
    const int m0  = blockIdx.x * BM;
    const int j0  = blockIdx.y * BK;

    const int srow = tid >> 3;
    const int scol = (tid & 7) * 4;

    float acc[8][8];
#pragma unroll
    for (int i = 0; i < 8; ++i)
#pragma unroll
        for (int j = 0; j < 8; ++j) acc[i][j] = 0.f;

    for (int dc = 0; dc < DIMD / BD; ++dc) {
        const int d0 = dc * BD;
        __syncthreads();
#pragma unroll
        for (int rr = 0; rr < 4; ++rr) {
            const int r = srow + rr * 32;
            float4 av = *(const float4*)&E[(size_t)(m0 + r) * DIMD + d0 + scol];
            As[(scol + 0) * LDS_STRIDE + r] = av.x;
            As[(scol + 1) * LDS_STRIDE + r] = av.y;
            As[(scol + 2) * LDS_STRIDE + r] = av.z;
            As[(scol + 3) * LDS_STRIDE + r] = av.w;
            float4 bv = *(const float4*)&W[(size_t)(j0 + r) * DIMD + d0 + scol];
            Bs[(scol + 0) * LDS_STRIDE + r] = bv.x;
            Bs[(scol + 1) * LDS_STRIDE + r] = bv.y;
            Bs[(scol + 2) * LDS_STRIDE + r] = bv.z;
            Bs[(scol + 3) * LDS_STRIDE + r] = bv.w;
        }
        __syncthreads();
#pragma unroll 4
        for (int d = 0; d < BD; ++d) {
            float4 a0 = *(float4*)&As[d * LDS_STRIDE + ty * 4];
            float4 a1 = *(float4*)&As[d * LDS_STRIDE + 64 + ty * 4];
            float4 b0 = *(float4*)&Bs[d * LDS_STRIDE + tx * 4];
            float4 b1 = *(float4*)&Bs[d * LDS_STRIDE + 64 + tx * 4];
            float a[8] = {a0.x, a0.y, a0.z, a0.w, a1.x, a1.y, a1.z, a1.w};
            float b[8] = {b0.x, b0.y, b0.z, b0.w, b1.x, b1.y, b1.z, b1.w};
#pragma unroll
            for (int i = 0; i < 8; ++i)
#pragma unroll
                for (int j = 0; j < 8; ++j) acc[i][j] = fmaf(a[i], b[j], acc[i][j]);
        }
    }

    float4 bja = *(const float4*)&bias[j0 + tx * 4];
    float4 bjb = *(const float4*)&bias[j0 + 64 + tx * 4];
#pragma unroll
    for (int i = 0; i < 8; ++i) {
        const int mloc = (i < 4) ? (ty * 4 + i) : (64 + ty * 4 + (i - 4));
        const size_t row = (size_t)(m0 + mloc) * DIMD;
        float o[8] = {acc[i][0] + bja.x, acc[i][1] + bja.y, acc[i][2] + bja.z, acc[i][3] + bja.w,
                      acc[i][4] + bjb.x, acc[i][5] + bjb.y, acc[i][6] + bjb.z, acc[i][7] + bjb.w};
        *(float4*)&C[row + j0 + tx * 4]      = *(float4*)&o[0];
        *(float4*)&C[row + j0 + 64 + tx * 4] = *(float4*)&o[4];
        ushort4 h0 = {f2bf(o[0]), f2bf(o[1]), f2bf(o[2]), f2bf(o[3])};
        ushort4 h1 = {f2bf(o[4]), f2bf(o[5]), f2bf(o[6]), f2bf(o[7])};
        *(ushort4*)&Cb[row + j0 + tx * 4]      = h0;
        *(ushort4*)&Cb[row + j0 + 64 + tx * 4] = h1;
    }
}

// -------------------------------------------------------------------------
// Kernel 2a: X -> xnorm + bf16 Xb (one wave per row)
// -------------------------------------------------------------------------
__global__ void convx_kernel(const float* __restrict__ X, float* __restrict__ xnorm,
                             unsigned short* __restrict__ Xb)
{
    const int wave = threadIdx.x >> 6;
    const int lane = threadIdx.x & 63;
    const int row  = blockIdx.x * 4 + wave;
    float4 v = *(const float4*)&X[(size_t)row * DIMD + lane * 4];
    ushort4 h = {f2bf(v.x), f2bf(v.y), f2bf(v.z), f2bf(v.w)};
    *(ushort4*)&Xb[(size_t)row * DIMD + lane * 4] = h;
    float s = v.x * v.x + v.y * v.y + v.z * v.z + v.w * v.w;
#pragma unroll
    for (int off = 1; off < 64; off <<= 1) s += __shfl_xor(s, off);
    if (lane == 0) xnorm[row] = s;
}

// Kernel 2b: cnorm from fp32 C
__global__ void cnorm_kernel(const float* __restrict__ A, float* __restrict__ out)
{
    const int wave = threadIdx.x >> 6;
    const int lane = threadIdx.x & 63;
    const int row  = blockIdx.x * 4 + wave;
    float4 v = *(const float4*)&A[(size_t)row * DIMD + lane * 4];
    float s = v.x * v.x + v.y * v.y + v.z * v.z + v.w * v.w;
#pragma unroll
    for (int off = 1; off < 64; off <<= 1) s += __shfl_xor(s, off);
    if (lane == 0) out[row] = s;
}

// -------------------------------------------------------------------------
// Kernel 3: bf16 MFMA distance GEMM + fused approx-argmin + candidate append.
// v[token][code] = cnorm[code] - 2*dot (xnorm dropped: per-token shift).
// Grid (NTOK/128, NCODE/1024). 4 waves; wave (wrow,wcol) owns a 64x64 quadrant.
// LDS rows XOR-swizzled (chunk ^= row&7) so global_load_lds stays contiguous
// while ds_read_b128 fragments spread across all 32 banks.
// -------------------------------------------------------------------------
__global__ __launch_bounds__(256, 3)
void mfma_argmin_kernel(const unsigned short* __restrict__ Xb,
                        const unsigned short* __restrict__ Cb,
                        const float* __restrict__ cnorm,
                        unsigned* __restrict__ list, unsigned* __restrict__ count,
                        unsigned cap)
{
    __shared__ unsigned short Xs[GBM * GBD];   // 16 KB, swizzled
    __shared__ unsigned short Cs[GBK * GBD];   // 16 KB

    const int tid  = threadIdx.x;
    const int lane = tid & 63;
    const int wv   = tid >> 6;
    const int wrow = wv & 1;          // token half
    const int wcol = wv >> 1;         // code half
    const int l15  = lane & 15;
    const int quad = lane >> 4;
    const int m0   = blockIdx.x * GBM;
    const int kblk = blockIdx.y * (GBK * KT);

    float runv[16], tm[16];
#pragma unroll
    for (int t = 0; t < 16; ++t) runv[t] = 3.4e38f;

    for (int kt = 0; kt < KT; ++kt) {
        const int k0 = kblk + kt * GBK;
        floatx4 acc[4][4];
#pragma unroll
        for (int i = 0; i < 4; ++i)
#pragma unroll
            for (int j = 0; j < 4; ++j) acc[i][j] = (floatx4){0.f, 0.f, 0.f, 0.f};

        for (int dc = 0; dc < DIMD / GBD; ++dc) {
            const int dstage = dc * GBD;
            __syncthreads();
#pragma unroll
            for (int q = 0; q < 4; ++q) {
                const int s = q * 256 + tid;
                const int row = s >> 3;
                const int chunk = (s & 7) ^ (row & 7);
                async_copy16(Xb + (size_t)(m0 + row) * DIMD + dstage + chunk * 8,
                             (char*)Xs + s * 16);
            }
#pragma unroll
            for (int q = 0; q < 4; ++q) {
                const int s = q * 256 + tid;
                const int row = s >> 3;
                const int chunk = (s & 7) ^ (row & 7);
                async_copy16(Cb + (size_t)(k0 + row) * DIMD + dstage + chunk * 8,
                             (char*)Cs + s * 16);
            }
            __syncthreads();
#pragma unroll
            for (int ks = 0; ks < 2; ++ks) {
                short8 aF[4], bF[4];
#pragma unroll
                for (int i = 0; i < 4; ++i) {
                    const int row = wrow * 64 + i * 16 + l15;
                    const int pos = (ks * 4 + quad) ^ (row & 7);
                    aF[i] = *(const short8*)((const char*)Xs + row * 128 + pos * 16);
                }
#pragma unroll
                for (int j = 0; j < 4; ++j) {
                    const int row = wcol * 64 + j * 16 + l15;
                    const int pos = (ks * 4 + quad) ^ (row & 7);
                    bF[j] = *(const short8*)((const char*)Cs + row * 128 + pos * 16);
                }
#pragma unroll
                for (int i = 0; i < 4; ++i)
#pragma unroll
                    for (int j = 0; j < 4; ++j)
                        acc[i][j] = __builtin_amdgcn_mfma_f32_16x16x32_bf16(
                            aF[i], bF[j], acc[i][j], 0, 0, 0);
            }
        }

        // ---- epilogue: pass 1, per-lane mins ----
        const int kl = k0 + wcol * 64 + l15;   // code of j=0 for this lane
        float cn[4];
#pragma unroll
        for (int j = 0; j < 4; ++j) cn[j] = cnorm[kl + j * 16];

#pragma unroll
        for (int i = 0; i < 4; ++i) {
#pragma unroll
            for (int reg = 0; reg < 4; ++reg) {
                const int t = i * 4 + reg;
                float v0 = fmaf(-2.f, acc[i][0][reg], cn[0]);
                float v1 = fmaf(-2.f, acc[i][1][reg], cn[1]);
                float v2 = fmaf(-2.f, acc[i][2][reg], cn[2]);
                float v3 = fmaf(-2.f, acc[i][3][reg], cn[3]);
                acc[i][0][reg] = v0; acc[i][1][reg] = v1;
                acc[i][2][reg] = v2; acc[i][3][reg] = v3;
                const float mm = fminf(fminf(v0, v1), fminf(v2, v3));
                tm[t] = mm;
                runv[t] = fminf(runv[t], mm);
            }
        }
        // butterfly across the 16 code-lanes (same quad = same tokens)
#pragma unroll
        for (int d = 1; d < 16; d <<= 1)
#pragma unroll
            for (int t = 0; t < 16; ++t)
                runv[t] = fminf(runv[t], __shfl_xor(runv[t], d));

        // ---- pass 2: append candidates within MARGIN of running min ----
#pragma unroll
        for (int i = 0; i < 4; ++i) {
#pragma unroll
            for (int reg = 0; reg < 4; ++reg) {
                const int t = i * 4 + reg;
                const float thr = runv[t] + MARGIN;
                if (tm[t] < thr) {
                    const unsigned token = m0 + wrow * 64 + i * 16 + quad * 4 + reg;
#pragma unroll
                    for (int j = 0; j < 4; ++j) {
                        if (acc[i][j][reg] < thr) {
                            unsigned pos = atomicAdd(count, 1u);
                            if (pos < cap)
                                list[pos] = (token << 13) | (unsigned)(kl + j * 16);
                        }
                    }
                }
            }
        }
    }
}

// -------------------------------------------------------------------------
// Kernel 4: exact fp32 rescore of candidates; packed (d_bits<<32 | code)
// global atomicMin per token -> lowest-index tie-break like np.argmin.
// -------------------------------------------------------------------------
__global__ __launch_bounds__(256)
void rescore_kernel(const float* __restrict__ X, const float* __restrict__ C,
                    const float* __restrict__ xnorm, const float* __restrict__ cnorm,
                    const unsigned* __restrict__ list, const unsigned* __restrict__ count,
                    unsigned cap, unsigned long long* __restrict__ fin)
{
    const int lane = threadIdx.x & 63;
    const int wid  = (blockIdx.x * 256 + threadIdx.x) >> 6;
    const int nw   = (gridDim.x * 256) >> 6;
    unsigned n = *count; if (n > cap) n = cap;

    for (unsigned c = wid; c < n; c += nw) {
        const unsigned e = list[c];
        const unsigned tok = e >> 13, code = e & 8191u;
        float4 x4 = *(const float4*)&X[(size_t)tok * DIMD + lane * 4];
        float4 c4 = *(const float4*)&C[(size_t)code * DIMD + lane * 4];
        float dot = x4.x * c4.x;
        dot = fmaf(x4.y, c4.y, dot);
        dot = fmaf(x4.z, c4.z, dot);
        dot = fmaf(x4.w, c4.w, dot);
#pragma unroll
        for (int d = 1; d < 64; d <<= 1) dot += __shfl_xor(dot, d);
        if (lane == 0) {
            const float dd = xnorm[tok] + cnorm[code] - 2.f * dot;
            const unsigned long long p =
                ((unsigned long long)__float_as_uint(dd) << 32) | code;
            atomicMin(&fin[tok], p);
        }
    }
}

// -------------------------------------------------------------------------
// Kernel 5: gather winner, straight-through output, loss. One wave/token.
// -------------------------------------------------------------------------
__global__ void finalize_kernel(const float* __restrict__ X, const float* __restrict__ C,
                                const unsigned long long* __restrict__ fin,
                                float* __restrict__ out)
{
    const int t    = blockIdx.x;
    const int lane = threadIdx.x;
    const unsigned code = (unsigned)(fin[t] & 0xFFFFFFFFull);

    float4 c4 = *(const float4*)&C[(size_t)code * DIMD + lane * 4];
    float4 x4 = *(const float4*)&X[(size_t)t * DIMD + lane * 4];
    float4 w  = {c4.x - x4.x, c4.y - x4.y, c4.z - x4.z, c4.w - x4.w};
    float ssq = w.x * w.x + w.y * w.y + w.z * w.z + w.w * w.w;
#pragma unroll
    for (int off = 1; off < 64; off <<= 1) ssq += __shfl_xor(ssq, off);

    float4 zq = {x4.x + w.x, x4.y + w.y, x4.z + w.z, x4.w + w.w};
    *(float4*)&out[(size_t)t * DIMD + lane * 4] = zq;

    if (lane == 0) {
        atomicAdd(&out[NELEM], ssq * (1.25f / (float)NELEM));
        out[NELEM + 1 + t] = (float)code;
    }
}

// -------------------------------------------------------------------------
extern "C" void kernel_launch(void* const* d_in, const int* in_sizes, int n_in,
                              void* d_out, int out_size, void* d_ws, size_t ws_size,
                              hipStream_t stream)
{
    const float* X = (const float*)d_in[0];
    const float* E = (const float*)d_in[1];
    const float* W = (const float*)d_in[2];
    const float* b = (const float*)d_in[3];
    float* out = (float*)d_out;

    char* w = (char*)d_ws;
    float* C            = (float*)w;           w += (size_t)NCODE * DIMD * 4;
    unsigned short* Xb  = (unsigned short*)w;  w += (size_t)NTOK * DIMD * 2;
    unsigned short* Cb  = (unsigned short*)w;  w += (size_t)NCODE * DIMD * 2;
    float* xnorm        = (float*)w;           w += (size_t)NTOK * 4;
    float* cnorm        = (float*)w;           w += (size_t)NCODE * 4;
    unsigned long long* fin = (unsigned long long*)w; w += (size_t)NTOK * 8;
    unsigned* cnt       = (unsigned*)w;        w += 256;
    unsigned* list      = (unsigned*)w;

    size_t used = (size_t)(w - (char*)d_ws);
    size_t avail = (ws_size > used) ? (ws_size - used) / 4 : 0;
    unsigned cap = (unsigned)((avail > 16777216u) ? 16777216u : avail);

    hipMemsetAsync(cnt, 0, 4, stream);
    hipMemsetAsync(fin, 0xFF, (size_t)NTOK * 8, stream);
    hipMemsetAsync(out + NELEM, 0, 4, stream);

    project_kernel<<<dim3(NCODE / BM, DIMD / BK), 256, 0, stream>>>(E, W, b, C, Cb);
    convx_kernel<<<NTOK / 4, 256, 0, stream>>>(X, xnorm, Xb);
    cnorm_kernel<<<NCODE / 4, 256, 0, stream>>>(C, cnorm);
    mfma_argmin_kernel<<<dim3(NTOK / GBM, NCODE / (GBK * KT)), 256, 0, stream>>>(
        Xb, Cb, cnorm, list, cnt, cap);
    rescore_kernel<<<1024, 256, 0, stream>>>(X, C, xnorm, cnorm, list, cnt, cap, fin);
    finalize_kernel<<<NTOK, 64, 0, stream>>>(X, C, fin, out);
}

// Round 3
// 841.828 us; speedup vs baseline: 15.9929x; 15.9929x over previous
//
#include <hip/hip_runtime.h>

// Problem constants
#define DIMD   256
#define NTOK   16384
#define NCODE  8192
#define NELEM  (NTOK * DIMD)

// fp32 project-GEMM tiling
#define BM 128
#define BK 128
#define BD 32
#define PAD 4
#define LDS_STRIDE (BM + PAD)

// MFMA distance-GEMM tiling
#define GBM 128          // tokens per block
#define GBK 128          // codes per k-tile
#define KT  8            // k-tiles per block -> 1024 codes/block
#define GBD 64           // d-chunk per LDS stage
#define MARGIN 0.5f      // > two-sided worst-case bf16 distance error (~0.41)
#define LDSCAP 4096      // per-block LDS candidate buffer entries

typedef float floatx4 __attribute__((ext_vector_type(4)));
typedef short short8  __attribute__((ext_vector_type(8)));

__device__ __forceinline__ unsigned short f2bf(float f) {
    unsigned u = __float_as_uint(f);
    unsigned r = (u + 0x7FFFu + ((u >> 16) & 1u)) >> 16;
    return (unsigned short)r;
}

__device__ __forceinline__ void async_copy16(const void* g, void* l) {
    __builtin_amdgcn_global_load_lds(
        (const __attribute__((address_space(1))) unsigned int*)g,
        (__attribute__((address_space(3))) unsigned int*)l, 16, 0, 0);
}

// -------------------------------------------------------------------------
// Kernel 1: codebook projection C[k][j] = sum_i E[k][i]*W[j][i] + b[j]
// (fp32) + bf16 copy Cb.
// -------------------------------------------------------------------------
__global__ __launch_bounds__(256, 3)
void project_kernel(const float* __restrict__ E, const float* __restrict__ W,
                    const float* __restrict__ bias, float* __restrict__ C,
                    unsigned short* __restrict__ Cb)
{
    __shared__ float smem[2 * BD * LDS_STRIDE];
    float* As = smem;
    float* Bs = smem + BD * LDS_STRIDE;

    const int tid = threadIdx.x;
    const int tx  = tid & 15;
    const int ty  = tid >> 4;
    const int m0  = blockIdx.x * BM;
    const int j0  = blockIdx.y * BK;

    const int srow = tid >> 3;
    const int scol = (tid & 7) * 4;

    float acc[8][8];
#pragma unroll
    for (int i = 0; i < 8; ++i)
#pragma unroll
        for (int j = 0; j < 8; ++j) acc[i][j] = 0.f;

    for (int dc = 0; dc < DIMD / BD; ++dc) {
        const int d0 = dc * BD;
        __syncthreads();
#pragma unroll
        for (int rr = 0; rr < 4; ++rr) {
            const int r = srow + rr * 32;
            float4 av = *(const float4*)&E[(size_t)(m0 + r) * DIMD + d0 + scol];
            As[(scol + 0) * LDS_STRIDE + r] = av.x;
            As[(scol + 1) * LDS_STRIDE + r] = av.y;
            As[(scol + 2) * LDS_STRIDE + r] = av.z;
            As[(scol + 3) * LDS_STRIDE + r] = av.w;
            float4 bv = *(const float4*)&W[(size_t)(j0 + r) * DIMD + d0 + scol];
            Bs[(scol + 0) * LDS_STRIDE + r] = bv.x;
            Bs[(scol + 1) * LDS_STRIDE + r] = bv.y;
            Bs[(scol + 2) * LDS_STRIDE + r] = bv.z;
            Bs[(scol + 3) * LDS_STRIDE + r] = bv.w;
        }
        __syncthreads();
#pragma unroll 4
        for (int d = 0; d < BD; ++d) {
            float4 a0 = *(float4*)&As[d * LDS_STRIDE + ty * 4];
            float4 a1 = *(float4*)&As[d * LDS_STRIDE + 64 + ty * 4];
            float4 b0 = *(float4*)&Bs[d * LDS_STRIDE + tx * 4];
            float4 b1 = *(float4*)&Bs[d * LDS_STRIDE + 64 + tx * 4];
            float a[8] = {a0.x, a0.y, a0.z, a0.w, a1.x, a1.y, a1.z, a1.w};
            float b[8] = {b0.x, b0.y, b0.z, b0.w, b1.x, b1.y, b1.z, b1.w};
#pragma unroll
            for (int i = 0; i < 8; ++i)
#pragma unroll
                for (int j = 0; j < 8; ++j) acc[i][j] = fmaf(a[i], b[j], acc[i][j]);
        }
    }

    float4 bja = *(const float4*)&bias[j0 + tx * 4];
    float4 bjb = *(const float4*)&bias[j0 + 64 + tx * 4];
#pragma unroll
    for (int i = 0; i < 8; ++i) {
        const int mloc = (i < 4) ? (ty * 4 + i) : (64 + ty * 4 + (i - 4));
        const size_t row = (size_t)(m0 + mloc) * DIMD;
        float o[8] = {acc[i][0] + bja.x, acc[i][1] + bja.y, acc[i][2] + bja.z, acc[i][3] + bja.w,
                      acc[i][4] + bjb.x, acc[i][5] + bjb.y, acc[i][6] + bjb.z, acc[i][7] + bjb.w};
        *(float4*)&C[row + j0 + tx * 4]      = *(float4*)&o[0];
        *(float4*)&C[row + j0 + 64 + tx * 4] = *(float4*)&o[4];
        ushort4 h0 = {f2bf(o[0]), f2bf(o[1]), f2bf(o[2]), f2bf(o[3])};
        ushort4 h1 = {f2bf(o[4]), f2bf(o[5]), f2bf(o[6]), f2bf(o[7])};
        *(ushort4*)&Cb[row + j0 + tx * 4]      = h0;
        *(ushort4*)&Cb[row + j0 + 64 + tx * 4] = h1;
    }
}

// -------------------------------------------------------------------------
// Kernel 2a: X -> xnorm + bf16 Xb
// -------------------------------------------------------------------------
__global__ void convx_kernel(const float* __restrict__ X, float* __restrict__ xnorm,
                             unsigned short* __restrict__ Xb)
{
    const int wave = threadIdx.x >> 6;
    const int lane = threadIdx.x & 63;
    const int row  = blockIdx.x * 4 + wave;
    float4 v = *(const float4*)&X[(size_t)row * DIMD + lane * 4];
    ushort4 h = {f2bf(v.x), f2bf(v.y), f2bf(v.z), f2bf(v.w)};
    *(ushort4*)&Xb[(size_t)row * DIMD + lane * 4] = h;
    float s = v.x * v.x + v.y * v.y + v.z * v.z + v.w * v.w;
#pragma unroll
    for (int off = 1; off < 64; off <<= 1) s += __shfl_xor(s, off);
    if (lane == 0) xnorm[row] = s;
}

__global__ void cnorm_kernel(const float* __restrict__ A, float* __restrict__ out)
{
    const int wave = threadIdx.x >> 6;
    const int lane = threadIdx.x & 63;
    const int row  = blockIdx.x * 4 + wave;
    float4 v = *(const float4*)&A[(size_t)row * DIMD + lane * 4];
    float s = v.x * v.x + v.y * v.y + v.z * v.z + v.w * v.w;
#pragma unroll
    for (int off = 1; off < 64; off <<= 1) s += __shfl_xor(s, off);
    if (lane == 0) out[row] = s;
}

// -------------------------------------------------------------------------
// Kernel 3: bf16 MFMA distance GEMM + fused approx-argmin + candidate append.
// Appends buffered in LDS (wave-aggregated ballot + LDS atomic), flushed
// once per block with a single global atomicAdd chunk reservation.
// -------------------------------------------------------------------------
__global__ __launch_bounds__(256, 3)
void mfma_argmin_kernel(const unsigned short* __restrict__ Xb,
                        const unsigned short* __restrict__ Cb,
                        const float* __restrict__ cnorm,
                        unsigned* __restrict__ list, unsigned* __restrict__ count,
                        unsigned cap)
{
    __shared__ unsigned short Xs[GBM * GBD];   // 16 KB, swizzled
    __shared__ unsigned short Cs[GBK * GBD];   // 16 KB
    __shared__ unsigned cbuf[LDSCAP];          // 16 KB candidate buffer
    __shared__ unsigned lcnt, gbase;

    const int tid  = threadIdx.x;
    const int lane = tid & 63;
    const int wv   = tid >> 6;
    const int wrow = wv & 1;
    const int wcol = wv >> 1;
    const int l15  = lane & 15;
    const int quad = lane >> 4;
    const int m0   = blockIdx.x * GBM;
    const int kblk = blockIdx.y * (GBK * KT);

    if (tid == 0) lcnt = 0;
    // (visibility covered by the first __syncthreads inside the dc loop)

    float runv[16], tm[16];
#pragma unroll
    for (int t = 0; t < 16; ++t) runv[t] = 3.4e38f;

    for (int kt = 0; kt < KT; ++kt) {
        const int k0 = kblk + kt * GBK;
        floatx4 acc[4][4];
#pragma unroll
        for (int i = 0; i < 4; ++i)
#pragma unroll
            for (int j = 0; j < 4; ++j) acc[i][j] = (floatx4){0.f, 0.f, 0.f, 0.f};

        for (int dc = 0; dc < DIMD / GBD; ++dc) {
            const int dstage = dc * GBD;
            __syncthreads();
#pragma unroll
            for (int q = 0; q < 4; ++q) {
                const int s = q * 256 + tid;
                const int row = s >> 3;
                const int chunk = (s & 7) ^ (row & 7);
                async_copy16(Xb + (size_t)(m0 + row) * DIMD + dstage + chunk * 8,
                             (char*)Xs + s * 16);
            }
#pragma unroll
            for (int q = 0; q < 4; ++q) {
                const int s = q * 256 + tid;
                const int row = s >> 3;
                const int chunk = (s & 7) ^ (row & 7);
                async_copy16(Cb + (size_t)(k0 + row) * DIMD + dstage + chunk * 8,
                             (char*)Cs + s * 16);
            }
            __syncthreads();
#pragma unroll
            for (int ks = 0; ks < 2; ++ks) {
                short8 aF[4], bF[4];
#pragma unroll
                for (int i = 0; i < 4; ++i) {
                    const int row = wrow * 64 + i * 16 + l15;
                    const int pos = (ks * 4 + quad) ^ (row & 7);
                    aF[i] = *(const short8*)((const char*)Xs + row * 128 + pos * 16);
                }
#pragma unroll
                for (int j = 0; j < 4; ++j) {
                    const int row = wcol * 64 + j * 16 + l15;
                    const int pos = (ks * 4 + quad) ^ (row & 7);
                    bF[j] = *(const short8*)((const char*)Cs + row * 128 + pos * 16);
                }
#pragma unroll
                for (int i = 0; i < 4; ++i)
#pragma unroll
                    for (int j = 0; j < 4; ++j)
                        acc[i][j] = __builtin_amdgcn_mfma_f32_16x16x32_bf16(
                            aF[i], bF[j], acc[i][j], 0, 0, 0);
            }
        }

        // ---- epilogue pass 1: distances + per-lane / cross-lane mins ----
        const int kl = k0 + wcol * 64 + l15;
        float cn[4];
#pragma unroll
        for (int j = 0; j < 4; ++j) cn[j] = cnorm[kl + j * 16];

#pragma unroll
        for (int i = 0; i < 4; ++i) {
#pragma unroll
            for (int reg = 0; reg < 4; ++reg) {
                const int t = i * 4 + reg;
                float v0 = fmaf(-2.f, acc[i][0][reg], cn[0]);
                float v1 = fmaf(-2.f, acc[i][1][reg], cn[1]);
                float v2 = fmaf(-2.f, acc[i][2][reg], cn[2]);
                float v3 = fmaf(-2.f, acc[i][3][reg], cn[3]);
                acc[i][0][reg] = v0; acc[i][1][reg] = v1;
                acc[i][2][reg] = v2; acc[i][3][reg] = v3;
                const float mm = fminf(fminf(v0, v1), fminf(v2, v3));
                tm[t] = mm;
                runv[t] = fminf(runv[t], mm);
            }
        }
#pragma unroll
        for (int d = 1; d < 16; d <<= 1)
#pragma unroll
            for (int t = 0; t < 16; ++t)
                runv[t] = fminf(runv[t], __shfl_xor(runv[t], d));

        // ---- pass 2: wave-aggregated LDS appends ----
#pragma unroll
        for (int i = 0; i < 4; ++i) {
#pragma unroll
            for (int reg = 0; reg < 4; ++reg) {
                const int t = i * 4 + reg;
                const float thr = runv[t] + MARGIN;
                if (__ballot(tm[t] < thr) == 0ull) continue;
                const unsigned token = m0 + wrow * 64 + i * 16 + quad * 4 + reg;
#pragma unroll
                for (int j = 0; j < 4; ++j) {
                    const bool cond = acc[i][j][reg] < thr;
                    const unsigned long long m = __ballot(cond);
                    if (m == 0ull) continue;
                    if (cond) {
                        const int leader = __ffsll((unsigned long long)m) - 1;
                        const unsigned prefix =
                            (unsigned)__popcll(m & ((1ull << lane) - 1ull));
                        unsigned base = 0;
                        if (lane == leader)
                            base = atomicAdd(&lcnt, (unsigned)__popcll(m));
                        base = __shfl(base, leader);
                        const unsigned pos = base + prefix;
                        const unsigned entry = (token << 13) | (unsigned)(kl + j * 16);
                        if (pos < LDSCAP) {
                            cbuf[pos] = entry;
                        } else {   // overflow fallback (rare) — still exact
                            unsigned g = atomicAdd(count, 1u);
                            if (g < cap) list[g] = entry;
                        }
                    }
                }
            }
        }
    }

    // ---- flush: one global atomic per block, coalesced writes ----
    __syncthreads();
    const unsigned n = (lcnt < LDSCAP) ? lcnt : LDSCAP;
    if (tid == 0) gbase = atomicAdd(count, n);
    __syncthreads();
    const unsigned gb = gbase;
    for (unsigned i = tid; i < n; i += 256) {
        const unsigned p = gb + i;
        if (p < cap) list[p] = cbuf[i];
    }
}

// -------------------------------------------------------------------------
// Kernel 4: exact fp32 rescore of candidates; packed (d_bits<<32 | code)
// atomicMin per token -> lowest-index tie-break like np.argmin.
// -------------------------------------------------------------------------
__global__ __launch_bounds__(256)
void rescore_kernel(const float* __restrict__ X, const float* __restrict__ C,
                    const float* __restrict__ xnorm, const float* __restrict__ cnorm,
                    const unsigned* __restrict__ list, const unsigned* __restrict__ count,
                    unsigned cap, unsigned long long* __restrict__ fin)
{
    const int lane = threadIdx.x & 63;
    const int wid  = (blockIdx.x * 256 + threadIdx.x) >> 6;
    const int nw   = (gridDim.x * 256) >> 6;
    unsigned n = *count; if (n > cap) n = cap;

    for (unsigned c = wid; c < n; c += nw) {
        const unsigned e = list[c];
        const unsigned tok = e >> 13, code = e & 8191u;
        float4 x4 = *(const float4*)&X[(size_t)tok * DIMD + lane * 4];
        float4 c4 = *(const float4*)&C[(size_t)code * DIMD + lane * 4];
        float dot = x4.x * c4.x;
        dot = fmaf(x4.y, c4.y, dot);
        dot = fmaf(x4.z, c4.z, dot);
        dot = fmaf(x4.w, c4.w, dot);
#pragma unroll
        for (int d = 1; d < 64; d <<= 1) dot += __shfl_xor(dot, d);
        if (lane == 0) {
            const float dd = xnorm[tok] + cnorm[code] - 2.f * dot;
            const unsigned long long p =
                ((unsigned long long)__float_as_uint(dd) << 32) | code;
            atomicMin(&fin[tok], p);
        }
    }
}

// -------------------------------------------------------------------------
// Kernel 5: gather winner, straight-through output, loss.
// 256 blocks x 256 threads; 64 tokens/block; per-lane loss partials,
// block-reduced -> ONE atomic per block (was 16384 same-line atomics).
// -------------------------------------------------------------------------
__global__ __launch_bounds__(256)
void finalize_kernel(const float* __restrict__ X, const float* __restrict__ C,
                     const unsigned long long* __restrict__ fin,
                     float* __restrict__ out)
{
    __shared__ float part[4];
    const int lane = threadIdx.x & 63;
    const int wv   = threadIdx.x >> 6;
    const int t0   = blockIdx.x * 64;

    float local = 0.f;
    for (int it = 0; it < 16; ++it) {
        const int t = t0 + wv * 16 + it;
        const unsigned code = (unsigned)(fin[t] & 0xFFFFFFFFull);
        float4 c4 = *(const float4*)&C[(size_t)code * DIMD + lane * 4];
        float4 x4 = *(const float4*)&X[(size_t)t * DIMD + lane * 4];
        float4 w  = {c4.x - x4.x, c4.y - x4.y, c4.z - x4.z, c4.w - x4.w};
        local += w.x * w.x + w.y * w.y + w.z * w.z + w.w * w.w;
        float4 zq = {x4.x + w.x, x4.y + w.y, x4.z + w.z, x4.w + w.w};
        *(float4*)&out[(size_t)t * DIMD + lane * 4] = zq;
        if (lane == 0) out[NELEM + 1 + t] = (float)code;
    }
#pragma unroll
    for (int off = 1; off < 64; off <<= 1) local += __shfl_xor(local, off);
    if (lane == 0) part[wv] = local;
    __syncthreads();
    if (threadIdx.x == 0) {
        const float s = part[0] + part[1] + part[2] + part[3];
        atomicAdd(&out[NELEM], s * (1.25f / (float)NELEM));
    }
}

// -------------------------------------------------------------------------
extern "C" void kernel_launch(void* const* d_in, const int* in_sizes, int n_in,
                              void* d_out, int out_size, void* d_ws, size_t ws_size,
                              hipStream_t stream)
{
    const float* X = (const float*)d_in[0];
    const float* E = (const float*)d_in[1];
    const float* W = (const float*)d_in[2];
    const float* b = (const float*)d_in[3];
    float* out = (float*)d_out;

    char* w = (char*)d_ws;
    float* C            = (float*)w;           w += (size_t)NCODE * DIMD * 4;
    unsigned short* Xb  = (unsigned short*)w;  w += (size_t)NTOK * DIMD * 2;
    unsigned short* Cb  = (unsigned short*)w;  w += (size_t)NCODE * DIMD * 2;
    float* xnorm        = (float*)w;           w += (size_t)NTOK * 4;
    float* cnorm        = (float*)w;           w += (size_t)NCODE * 4;
    unsigned long long* fin = (unsigned long long*)w; w += (size_t)NTOK * 8;
    unsigned* cnt       = (unsigned*)w;        w += 256;
    unsigned* list      = (unsigned*)w;

    size_t used = (size_t)(w - (char*)d_ws);
    size_t avail = (ws_size > used) ? (ws_size - used) / 4 : 0;
    unsigned cap = (unsigned)((avail > 16777216u) ? 16777216u : avail);

    hipMemsetAsync(cnt, 0, 4, stream);
    hipMemsetAsync(fin, 0xFF, (size_t)NTOK * 8, stream);
    hipMemsetAsync(out + NELEM, 0, 4, stream);

    project_kernel<<<dim3(NCODE / BM, DIMD / BK), 256, 0, stream>>>(E, W, b, C, Cb);
    convx_kernel<<<NTOK / 4, 256, 0, stream>>>(X, xnorm, Xb);
    cnorm_kernel<<<NCODE / 4, 256, 0, stream>>>(C, cnorm);
    mfma_argmin_kernel<<<dim3(NTOK / GBM, NCODE / (GBK * KT)), 256, 0, stream>>>(
        Xb, Cb, cnorm, list, cnt, cap);
    rescore_kernel<<<1024, 256, 0, stream>>>(X, C, xnorm, cnorm, list, cnt, cap, fin);
    finalize_kernel<<<NTOK / 64, 256, 0, stream>>>(X, C, fin, out);
}

// Round 4
// 353.871 us; speedup vs baseline: 38.0458x; 2.3789x over previous
//
#include <hip/hip_runtime.h>

// Problem constants
#define DIMD   256
#define NTOK   16384
#define NCODE  8192
#define NELEM  (NTOK * DIMD)

// fp32 project-GEMM tiling
#define BM 128
#define BK 128
#define BD 32
#define PAD 4
#define LDS_STRIDE (BM + PAD)

// MFMA distance-GEMM tiling
#define GBM 128          // tokens per block
#define GBK 128          // codes per k-tile
#define KT  16           // k-tiles per block -> 2048 codes/block
#define SPLITS 4
#define GBD 64           // d-chunk per LDS stage
#define MARGIN 0.5f      // > two-sided worst-case bf16 distance error (~0.4)
#define LDSCAP 4096      // raw per-block candidate buffer entries
#define FCAP   2048      // filtered buffer entries

typedef float floatx4 __attribute__((ext_vector_type(4)));
typedef short short8  __attribute__((ext_vector_type(8)));

__device__ __forceinline__ unsigned short f2bf(float f) {
    unsigned u = __float_as_uint(f);
    unsigned r = (u + 0x7FFFu + ((u >> 16) & 1u)) >> 16;
    return (unsigned short)r;
}

__device__ __forceinline__ void async_copy16(const void* g, void* l) {
    __builtin_amdgcn_global_load_lds(
        (const __attribute__((address_space(1))) unsigned int*)g,
        (__attribute__((address_space(3))) unsigned int*)l, 16, 0, 0);
}

// -------------------------------------------------------------------------
// Kernel 1: codebook projection C[k][j] = sum_i E[k][i]*W[j][i] + b[j]
// (fp32) + bf16 copy Cb.
// -------------------------------------------------------------------------
__global__ __launch_bounds__(256, 3)
void project_kernel(const float* __restrict__ E, const float* __restrict__ W,
                    const float* __restrict__ bias, float* __restrict__ C,
                    unsigned short* __restrict__ Cb)
{
    __shared__ float smem[2 * BD * LDS_STRIDE];
    float* As = smem;
    float* Bs = smem + BD * LDS_STRIDE;

    const int tid = threadIdx.x;
    const int tx  = tid & 15;
    const int ty  = tid >> 4;
    const int m0  = blockIdx.x * BM;
    const int j0  = blockIdx.y * BK;

    const int srow = tid >> 3;
    const int scol = (tid & 7) * 4;

    float acc[8][8];
#pragma unroll
    for (int i = 0; i < 8; ++i)
#pragma unroll
        for (int j = 0; j < 8; ++j) acc[i][j] = 0.f;

    for (int dc = 0; dc < DIMD / BD; ++dc) {
        const int d0 = dc * BD;
        __syncthreads();
#pragma unroll
        for (int rr = 0; rr < 4; ++rr) {
            const int r = srow + rr * 32;
            float4 av = *(const float4*)&E[(size_t)(m0 + r) * DIMD + d0 + scol];
            As[(scol + 0) * LDS_STRIDE + r] = av.x;
            As[(scol + 1) * LDS_STRIDE + r] = av.y;
            As[(scol + 2) * LDS_STRIDE + r] = av.z;
            As[(scol + 3) * LDS_STRIDE + r] = av.w;
            float4 bv = *(const float4*)&W[(size_t)(j0 + r) * DIMD + d0 + scol];
            Bs[(scol + 0) * LDS_STRIDE + r] = bv.x;
            Bs[(scol + 1) * LDS_STRIDE + r] = bv.y;
            Bs[(scol + 2) * LDS_STRIDE + r] = bv.z;
            Bs[(scol + 3) * LDS_STRIDE + r] = bv.w;
        }
        __syncthreads();
#pragma unroll 4
        for (int d = 0; d < BD; ++d) {
            float4 a0 = *(float4*)&As[d * LDS_STRIDE + ty * 4];
            float4 a1 = *(float4*)&As[d * LDS_STRIDE + 64 + ty * 4];
            float4 b0 = *(float4*)&Bs[d * LDS_STRIDE + tx * 4];
            float4 b1 = *(float4*)&Bs[d * LDS_STRIDE + 64 + tx * 4];
            float a[8] = {a0.x, a0.y, a0.z, a0.w, a1.x, a1.y, a1.z, a1.w};
            float b[8] = {b0.x, b0.y, b0.z, b0.w, b1.x, b1.y, b1.z, b1.w};
#pragma unroll
            for (int i = 0; i < 8; ++i)
#pragma unroll
                for (int j = 0; j < 8; ++j) acc[i][j] = fmaf(a[i], b[j], acc[i][j]);
        }
    }

    float4 bja = *(const float4*)&bias[j0 + tx * 4];
    float4 bjb = *(const float4*)&bias[j0 + 64 + tx * 4];
#pragma unroll
    for (int i = 0; i < 8; ++i) {
        const int mloc = (i < 4) ? (ty * 4 + i) : (64 + ty * 4 + (i - 4));
        const size_t row = (size_t)(m0 + mloc) * DIMD;
        float o[8] = {acc[i][0] + bja.x, acc[i][1] + bja.y, acc[i][2] + bja.z, acc[i][3] + bja.w,
                      acc[i][4] + bjb.x, acc[i][5] + bjb.y, acc[i][6] + bjb.z, acc[i][7] + bjb.w};
        *(float4*)&C[row + j0 + tx * 4]      = *(float4*)&o[0];
        *(float4*)&C[row + j0 + 64 + tx * 4] = *(float4*)&o[4];
        ushort4 h0 = {f2bf(o[0]), f2bf(o[1]), f2bf(o[2]), f2bf(o[3])};
        ushort4 h1 = {f2bf(o[4]), f2bf(o[5]), f2bf(o[6]), f2bf(o[7])};
        *(ushort4*)&Cb[row + j0 + tx * 4]      = h0;
        *(ushort4*)&Cb[row + j0 + 64 + tx * 4] = h1;
    }
}

// -------------------------------------------------------------------------
// Kernel 2a: X -> xnorm + bf16 Xb
// -------------------------------------------------------------------------
__global__ void convx_kernel(const float* __restrict__ X, float* __restrict__ xnorm,
                             unsigned short* __restrict__ Xb)
{
    const int wave = threadIdx.x >> 6;
    const int lane = threadIdx.x & 63;
    const int row  = blockIdx.x * 4 + wave;
    float4 v = *(const float4*)&X[(size_t)row * DIMD + lane * 4];
    ushort4 h = {f2bf(v.x), f2bf(v.y), f2bf(v.z), f2bf(v.w)};
    *(ushort4*)&Xb[(size_t)row * DIMD + lane * 4] = h;
    float s = v.x * v.x + v.y * v.y + v.z * v.z + v.w * v.w;
#pragma unroll
    for (int off = 1; off < 64; off <<= 1) s += __shfl_xor(s, off);
    if (lane == 0) xnorm[row] = s;
}

__global__ void cnorm_kernel(const float* __restrict__ A, float* __restrict__ out)
{
    const int wave = threadIdx.x >> 6;
    const int lane = threadIdx.x & 63;
    const int row  = blockIdx.x * 4 + wave;
    float4 v = *(const float4*)&A[(size_t)row * DIMD + lane * 4];
    float s = v.x * v.x + v.y * v.y + v.z * v.z + v.w * v.w;
#pragma unroll
    for (int off = 1; off < 64; off <<= 1) s += __shfl_xor(s, off);
    if (lane == 0) out[row] = s;
}

// -------------------------------------------------------------------------
// Kernel 3: bf16 MFMA distance GEMM + fused approx-argmin + candidate append.
// LDS-buffered appends (with approx value), flush-time filter against the
// FINAL per-token split-min + MARGIN, single global chunk reservation.
// -------------------------------------------------------------------------
__global__ __launch_bounds__(256, 2)
void mfma_argmin_kernel(const unsigned short* __restrict__ Xb,
                        const unsigned short* __restrict__ Cb,
                        const float* __restrict__ cnorm,
                        unsigned* __restrict__ list, unsigned* __restrict__ count,
                        unsigned cap)
{
    __shared__ unsigned short Xs[GBM * GBD];   // 16 KB, swizzled
    __shared__ unsigned short Cs[GBK * GBD];   // 16 KB
    __shared__ unsigned cbuf[LDSCAP];          // 16 KB raw candidates
    __shared__ float    cval[LDSCAP];          // 16 KB approx distances
    __shared__ unsigned fbuf[FCAP];            // 8 KB filtered candidates
    __shared__ float    wmin[2 * GBM];         // per-wcol per-token mins
    __shared__ float    tokmin[GBM];
    __shared__ unsigned lcnt, fcnt, gbase;

    const int tid  = threadIdx.x;
    const int lane = tid & 63;
    const int wv   = tid >> 6;
    const int wrow = wv & 1;
    const int wcol = wv >> 1;
    const int l15  = lane & 15;
    const int quad = lane >> 4;
    const int m0   = blockIdx.x * GBM;
    const int kblk = blockIdx.y * (GBK * KT);

    if (tid == 0) { lcnt = 0; fcnt = 0; }
    // visibility covered by the first __syncthreads inside the dc loop

    float runv[16], tm[16];
#pragma unroll
    for (int t = 0; t < 16; ++t) runv[t] = 3.4e38f;

    for (int kt = 0; kt < KT; ++kt) {
        const int k0 = kblk + kt * GBK;
        floatx4 acc[4][4];
#pragma unroll
        for (int i = 0; i < 4; ++i)
#pragma unroll
            for (int j = 0; j < 4; ++j) acc[i][j] = (floatx4){0.f, 0.f, 0.f, 0.f};

        for (int dc = 0; dc < DIMD / GBD; ++dc) {
            const int dstage = dc * GBD;
            __syncthreads();
#pragma unroll
            for (int q = 0; q < 4; ++q) {
                const int s = q * 256 + tid;
                const int row = s >> 3;
                const int chunk = (s & 7) ^ (row & 7);
                async_copy16(Xb + (size_t)(m0 + row) * DIMD + dstage + chunk * 8,
                             (char*)Xs + s * 16);
            }
#pragma unroll
            for (int q = 0; q < 4; ++q) {
                const int s = q * 256 + tid;
                const int row = s >> 3;
                const int chunk = (s & 7) ^ (row & 7);
                async_copy16(Cb + (size_t)(k0 + row) * DIMD + dstage + chunk * 8,
                             (char*)Cs + s * 16);
            }
            __syncthreads();
#pragma unroll
            for (int ks = 0; ks < 2; ++ks) {
                short8 aF[4], bF[4];
#pragma unroll
                for (int i = 0; i < 4; ++i) {
                    const int row = wrow * 64 + i * 16 + l15;
                    const int pos = (ks * 4 + quad) ^ (row & 7);
                    aF[i] = *(const short8*)((const char*)Xs + row * 128 + pos * 16);
                }
#pragma unroll
                for (int j = 0; j < 4; ++j) {
                    const int row = wcol * 64 + j * 16 + l15;
                    const int pos = (ks * 4 + quad) ^ (row & 7);
                    bF[j] = *(const short8*)((const char*)Cs + row * 128 + pos * 16);
                }
#pragma unroll
                for (int i = 0; i < 4; ++i)
#pragma unroll
                    for (int j = 0; j < 4; ++j)
                        acc[i][j] = __builtin_amdgcn_mfma_f32_16x16x32_bf16(
                            aF[i], bF[j], acc[i][j], 0, 0, 0);
            }
        }

        // ---- epilogue pass 1: distances + per-lane / cross-lane mins ----
        const int kl = k0 + wcol * 64 + l15;
        float cn[4];
#pragma unroll
        for (int j = 0; j < 4; ++j) cn[j] = cnorm[kl + j * 16];

#pragma unroll
        for (int i = 0; i < 4; ++i) {
#pragma unroll
            for (int reg = 0; reg < 4; ++reg) {
                const int t = i * 4 + reg;
                float v0 = fmaf(-2.f, acc[i][0][reg], cn[0]);
                float v1 = fmaf(-2.f, acc[i][1][reg], cn[1]);
                float v2 = fmaf(-2.f, acc[i][2][reg], cn[2]);
                float v3 = fmaf(-2.f, acc[i][3][reg], cn[3]);
                acc[i][0][reg] = v0; acc[i][1][reg] = v1;
                acc[i][2][reg] = v2; acc[i][3][reg] = v3;
                const float mm = fminf(fminf(v0, v1), fminf(v2, v3));
                tm[t] = mm;
                runv[t] = fminf(runv[t], mm);
            }
        }
#pragma unroll
        for (int d = 1; d < 16; d <<= 1)
#pragma unroll
            for (int t = 0; t < 16; ++t)
                runv[t] = fminf(runv[t], __shfl_xor(runv[t], d));

        // ---- pass 2: wave-aggregated LDS appends (value kept for filter) --
#pragma unroll
        for (int i = 0; i < 4; ++i) {
#pragma unroll
            for (int reg = 0; reg < 4; ++reg) {
                const int t = i * 4 + reg;
                const float thr = runv[t] + MARGIN;
                if (__ballot(tm[t] < thr) == 0ull) continue;
                const unsigned token = m0 + wrow * 64 + i * 16 + quad * 4 + reg;
#pragma unroll
                for (int j = 0; j < 4; ++j) {
                    const bool cond = acc[i][j][reg] < thr;
                    const unsigned long long m = __ballot(cond);
                    if (m == 0ull) continue;
                    if (cond) {
                        const int leader = __ffsll((unsigned long long)m) - 1;
                        const unsigned prefix =
                            (unsigned)__popcll(m & ((1ull << lane) - 1ull));
                        unsigned base = 0;
                        if (lane == leader)
                            base = atomicAdd(&lcnt, (unsigned)__popcll(m));
                        base = __shfl(base, leader);
                        const unsigned pos = base + prefix;
                        const unsigned entry = (token << 13) | (unsigned)(kl + j * 16);
                        if (pos < LDSCAP) {
                            cbuf[pos] = entry;
                            cval[pos] = acc[i][j][reg];
                        } else {   // overflow fallback (rare) — exact, unfiltered
                            unsigned g = atomicAdd(count, 1u);
                            if (g < cap) list[g] = entry;
                        }
                    }
                }
            }
        }
    }

    // ---- final per-token split-min across waves ----
    __syncthreads();
    if (l15 == 0) {
#pragma unroll
        for (int i = 0; i < 4; ++i)
#pragma unroll
            for (int reg = 0; reg < 4; ++reg) {
                const int tl = wrow * 64 + i * 16 + quad * 4 + reg;
                wmin[wcol * GBM + tl] = runv[i * 4 + reg];
            }
    }
    __syncthreads();
    if (tid < GBM) tokmin[tid] = fminf(wmin[tid], wmin[GBM + tid]) + MARGIN;
    __syncthreads();

    // ---- filter raw candidates against FINAL min + margin ----
    const unsigned nn = (lcnt < LDSCAP) ? lcnt : LDSCAP;
    for (unsigned i = tid; i < nn; i += 256) {
        const unsigned e = cbuf[i];
        const float v = cval[i];
        const unsigned tl = (e >> 13) - (unsigned)m0;
        if (v < tokmin[tl]) {
            unsigned p = atomicAdd(&fcnt, 1u);
            if (p < FCAP) fbuf[p] = e;
            else { unsigned g = atomicAdd(count, 1u); if (g < cap) list[g] = e; }
        }
    }
    __syncthreads();

    // ---- flush: one global atomic per block, coalesced writes ----
    const unsigned fn = (fcnt < FCAP) ? fcnt : FCAP;
    if (tid == 0) gbase = atomicAdd(count, fn);
    __syncthreads();
    const unsigned gb = gbase;
    for (unsigned i = tid; i < fn; i += 256) {
        const unsigned p = gb + i;
        if (p < cap) list[p] = fbuf[i];
    }
}

// -------------------------------------------------------------------------
// Kernel 4: exact fp32 rescore. 16-lane groups, 4 candidates per wave,
// 8 independent float4 loads in flight per candidate. Packed
// (d_bits<<32 | code) atomicMin -> lowest-index tie-break like np.argmin.
// -------------------------------------------------------------------------
__global__ __launch_bounds__(256)
void rescore_kernel(const float* __restrict__ X, const float* __restrict__ C,
                    const float* __restrict__ xnorm, const float* __restrict__ cnorm,
                    const unsigned* __restrict__ list, const unsigned* __restrict__ count,
                    unsigned cap, unsigned long long* __restrict__ fin)
{
    const int lane = threadIdx.x & 63;
    const int g16  = lane & 15;
    const int sub  = lane >> 4;
    const int gid  = ((blockIdx.x * 256 + threadIdx.x) >> 6) * 4 + sub;
    const int ng   = ((gridDim.x * 256) >> 6) * 4;
    unsigned n = *count; if (n > cap) n = cap;

    for (unsigned c = gid; c < n; c += ng) {
        const unsigned e = list[c];
        const unsigned tok = e >> 13, code = e & 8191u;
        const float* xr = &X[(size_t)tok * DIMD];
        const float* cr = &C[(size_t)code * DIMD];
        float dot = 0.f;
#pragma unroll
        for (int r = 0; r < 4; ++r) {
            float4 x4 = *(const float4*)&xr[r * 64 + g16 * 4];
            float4 c4 = *(const float4*)&cr[r * 64 + g16 * 4];
            dot = fmaf(x4.x, c4.x, dot);
            dot = fmaf(x4.y, c4.y, dot);
            dot = fmaf(x4.z, c4.z, dot);
            dot = fmaf(x4.w, c4.w, dot);
        }
#pragma unroll
        for (int d = 1; d < 16; d <<= 1) dot += __shfl_xor(dot, d);
        if (g16 == 0) {
            const float dd = xnorm[tok] + cnorm[code] - 2.f * dot;
            const unsigned long long p =
                ((unsigned long long)__float_as_uint(dd) << 32) | code;
            atomicMin(&fin[tok], p);
        }
    }
}

// -------------------------------------------------------------------------
// Kernel 5: gather winner, straight-through output, loss. One atomic/block.
// -------------------------------------------------------------------------
__global__ __launch_bounds__(256)
void finalize_kernel(const float* __restrict__ X, const float* __restrict__ C,
                     const unsigned long long* __restrict__ fin,
                     float* __restrict__ out)
{
    __shared__ float part[4];
    const int lane = threadIdx.x & 63;
    const int wv   = threadIdx.x >> 6;
    const int t0   = blockIdx.x * 64;

    float local = 0.f;
    for (int it = 0; it < 16; ++it) {
        const int t = t0 + wv * 16 + it;
        const unsigned code = (unsigned)(fin[t] & 0xFFFFFFFFull);
        float4 c4 = *(const float4*)&C[(size_t)code * DIMD + lane * 4];
        float4 x4 = *(const float4*)&X[(size_t)t * DIMD + lane * 4];
        float4 w  = {c4.x - x4.x, c4.y - x4.y, c4.z - x4.z, c4.w - x4.w};
        local += w.x * w.x + w.y * w.y + w.z * w.z + w.w * w.w;
        float4 zq = {x4.x + w.x, x4.y + w.y, x4.z + w.z, x4.w + w.w};
        *(float4*)&out[(size_t)t * DIMD + lane * 4] = zq;
        if (lane == 0) out[NELEM + 1 + t] = (float)code;
    }
#pragma unroll
    for (int off = 1; off < 64; off <<= 1) local += __shfl_xor(local, off);
    if (lane == 0) part[wv] = local;
    __syncthreads();
    if (threadIdx.x == 0) {
        const float s = part[0] + part[1] + part[2] + part[3];
        atomicAdd(&out[NELEM], s * (1.25f / (float)NELEM));
    }
}

// -------------------------------------------------------------------------
extern "C" void kernel_launch(void* const* d_in, const int* in_sizes, int n_in,
                              void* d_out, int out_size, void* d_ws, size_t ws_size,
                              hipStream_t stream)
{
    const float* X = (const float*)d_in[0];
    const float* E = (const float*)d_in[1];
    const float* W = (const float*)d_in[2];
    const float* b = (const float*)d_in[3];
    float* out = (float*)d_out;

    char* w = (char*)d_ws;
    float* C            = (float*)w;           w += (size_t)NCODE * DIMD * 4;
    unsigned short* Xb  = (unsigned short*)w;  w += (size_t)NTOK * DIMD * 2;
    unsigned short* Cb  = (unsigned short*)w;  w += (size_t)NCODE * DIMD * 2;
    float* xnorm        = (float*)w;           w += (size_t)NTOK * 4;
    float* cnorm        = (float*)w;           w += (size_t)NCODE * 4;
    unsigned long long* fin = (unsigned long long*)w; w += (size_t)NTOK * 8;
    unsigned* cnt       = (unsigned*)w;        w += 256;
    unsigned* list      = (unsigned*)w;

    size_t used = (size_t)(w - (char*)d_ws);
    size_t avail = (ws_size > used) ? (ws_size - used) / 4 : 0;
    unsigned cap = (unsigned)((avail > 16777216u) ? 16777216u : avail);

    hipMemsetAsync(cnt, 0, 4, stream);
    hipMemsetAsync(fin, 0xFF, (size_t)NTOK * 8, stream);
    hipMemsetAsync(out + NELEM, 0, 4, stream);

    project_kernel<<<dim3(NCODE / BM, DIMD / BK), 256, 0, stream>>>(E, W, b, C, Cb);
    convx_kernel<<<NTOK / 4, 256, 0, stream>>>(X, xnorm, Xb);
    cnorm_kernel<<<NCODE / 4, 256, 0, stream>>>(C, cnorm);
    mfma_argmin_kernel<<<dim3(NTOK / GBM, SPLITS), 256, 0, stream>>>(
        Xb, Cb, cnorm, list, cnt, cap);
    rescore_kernel<<<1024, 256, 0, stream>>>(X, C, xnorm, cnorm, list, cnt, cap, fin);
    finalize_kernel<<<NTOK / 64, 256, 0, stream>>>(X, C, fin, out);
}

// Round 5
// 349.830 us; speedup vs baseline: 38.4853x; 1.0116x over previous
//
#include <hip/hip_runtime.h>

// Problem constants
#define DIMD   256
#define NTOK   16384
#define NCODE  8192
#define NELEM  (NTOK * DIMD)

// fp32 project-GEMM tiling
#define BM 128
#define BK 128
#define BD 32
#define PAD 4
#define LDS_STRIDE (BM + PAD)

// streaming distance kernel
#define SPLITS_B 2                    // grid.y code splits
#define CODES_PER_WAVE (NCODE / SPLITS_B / 4)   // 1024
#define NGROUPS (CODES_PER_WAVE / 16)           // 64
#define MARGIN 0.5f                   // > two-sided worst-case bf16 distance error (~0.33)
#define LDSCAP 6144                   // raw per-block candidate entries
#define FCAP   2048                   // filtered entries

typedef float floatx4 __attribute__((ext_vector_type(4)));
typedef short short8  __attribute__((ext_vector_type(8)));

__device__ __forceinline__ unsigned short f2bf(float f) {
    unsigned u = __float_as_uint(f);
    unsigned r = (u + 0x7FFFu + ((u >> 16) & 1u)) >> 16;
    return (unsigned short)r;
}

// -------------------------------------------------------------------------
// Kernel 1: codebook projection C[k][j] = sum_i E[k][i]*W[j][i] + b[j]
// (fp32) + bf16 copy Cb.
// -------------------------------------------------------------------------
__global__ __launch_bounds__(256, 3)
void project_kernel(const float* __restrict__ E, const float* __restrict__ W,
                    const float* __restrict__ bias, float* __restrict__ C,
                    unsigned short* __restrict__ Cb)
{
    __shared__ float smem[2 * BD * LDS_STRIDE];
    float* As = smem;
    float* Bs = smem + BD * LDS_STRIDE;

    const int tid = threadIdx.x;
    const int tx  = tid & 15;
    const int ty  = tid >> 4;
    const int m0  = blockIdx.x * BM;
    const int j0  = blockIdx.y * BK;

    const int srow = tid >> 3;
    const int scol = (tid & 7) * 4;

    float acc[8][8];
#pragma unroll
    for (int i = 0; i < 8; ++i)
#pragma unroll
        for (int j = 0; j < 8; ++j) acc[i][j] = 0.f;

    for (int dc = 0; dc < DIMD / BD; ++dc) {
        const int d0 = dc * BD;
        __syncthreads();
#pragma unroll
        for (int rr = 0; rr < 4; ++rr) {
            const int r = srow + rr * 32;
            float4 av = *(const float4*)&E[(size_t)(m0 + r) * DIMD + d0 + scol];
            As[(scol + 0) * LDS_STRIDE + r] = av.x;
            As[(scol + 1) * LDS_STRIDE + r] = av.y;
            As[(scol + 2) * LDS_STRIDE + r] = av.z;
            As[(scol + 3) * LDS_STRIDE + r] = av.w;
            float4 bv = *(const float4*)&W[(size_t)(j0 + r) * DIMD + d0 + scol];
            Bs[(scol + 0) * LDS_STRIDE + r] = bv.x;
            Bs[(scol + 1) * LDS_STRIDE + r] = bv.y;
            Bs[(scol + 2) * LDS_STRIDE + r] = bv.z;
            Bs[(scol + 3) * LDS_STRIDE + r] = bv.w;
        }
        __syncthreads();
#pragma unroll 4
        for (int d = 0; d < BD; ++d) {
            float4 a0 = *(float4*)&As[d * LDS_STRIDE + ty * 4];
            float4 a1 = *(float4*)&As[d * LDS_STRIDE + 64 + ty * 4];
            float4 b0 = *(float4*)&Bs[d * LDS_STRIDE + tx * 4];
            float4 b1 = *(float4*)&Bs[d * LDS_STRIDE + 64 + tx * 4];
            float a[8] = {a0.x, a0.y, a0.z, a0.w, a1.x, a1.y, a1.z, a1.w};
            float b[8] = {b0.x, b0.y, b0.z, b0.w, b1.x, b1.y, b1.z, b1.w};
#pragma unroll
            for (int i = 0; i < 8; ++i)
#pragma unroll
                for (int j = 0; j < 8; ++j) acc[i][j] = fmaf(a[i], b[j], acc[i][j]);
        }
    }

    float4 bja = *(const float4*)&bias[j0 + tx * 4];
    float4 bjb = *(const float4*)&bias[j0 + 64 + tx * 4];
#pragma unroll
    for (int i = 0; i < 8; ++i) {
        const int mloc = (i < 4) ? (ty * 4 + i) : (64 + ty * 4 + (i - 4));
        const size_t row = (size_t)(m0 + mloc) * DIMD;
        float o[8] = {acc[i][0] + bja.x, acc[i][1] + bja.y, acc[i][2] + bja.z, acc[i][3] + bja.w,
                      acc[i][4] + bjb.x, acc[i][5] + bjb.y, acc[i][6] + bjb.z, acc[i][7] + bjb.w};
        *(float4*)&C[row + j0 + tx * 4]      = *(float4*)&o[0];
        *(float4*)&C[row + j0 + 64 + tx * 4] = *(float4*)&o[4];
        ushort4 h0 = {f2bf(o[0]), f2bf(o[1]), f2bf(o[2]), f2bf(o[3])};
        ushort4 h1 = {f2bf(o[4]), f2bf(o[5]), f2bf(o[6]), f2bf(o[7])};
        *(ushort4*)&Cb[row + j0 + tx * 4]      = h0;
        *(ushort4*)&Cb[row + j0 + 64 + tx * 4] = h1;
    }
}

// -------------------------------------------------------------------------
// Kernel 2a: X -> xnorm + bf16 Xb
// -------------------------------------------------------------------------
__global__ void convx_kernel(const float* __restrict__ X, float* __restrict__ xnorm,
                             unsigned short* __restrict__ Xb)
{
    const int wave = threadIdx.x >> 6;
    const int lane = threadIdx.x & 63;
    const int row  = blockIdx.x * 4 + wave;
    float4 v = *(const float4*)&X[(size_t)row * DIMD + lane * 4];
    ushort4 h = {f2bf(v.x), f2bf(v.y), f2bf(v.z), f2bf(v.w)};
    *(ushort4*)&Xb[(size_t)row * DIMD + lane * 4] = h;
    float s = v.x * v.x + v.y * v.y + v.z * v.z + v.w * v.w;
#pragma unroll
    for (int off = 1; off < 64; off <<= 1) s += __shfl_xor(s, off);
    if (lane == 0) xnorm[row] = s;
}

__global__ void cnorm_kernel(const float* __restrict__ A, float* __restrict__ out)
{
    const int wave = threadIdx.x >> 6;
    const int lane = threadIdx.x & 63;
    const int row  = blockIdx.x * 4 + wave;
    float4 v = *(const float4*)&A[(size_t)row * DIMD + lane * 4];
    float s = v.x * v.x + v.y * v.y + v.z * v.z + v.w * v.w;
#pragma unroll
    for (int off = 1; off < 64; off <<= 1) s += __shfl_xor(s, off);
    if (lane == 0) out[row] = s;
}

// -------------------------------------------------------------------------
// Kernel 3: barrier-free streaming distance + argmin-candidate kernel.
// Block = 4 waves sharing 64 tokens; wave w scans codes
// [blockIdx.y*4096 + w*1024, +1024) in groups of 16.
// A-fragments register-resident (loop-invariant); B-fragments stream from
// L2 via global_load_dwordx4 (frag layout == row-major 8 contiguous k).
// Approx d = cnorm - 2*dot; per-lane running min; stale per-token threshold
// (butterfly every 8 groups; stale => superset => exact). Block-end filter
// against 4-wave final min + MARGIN, single global chunk flush.
// -------------------------------------------------------------------------
__global__ __launch_bounds__(256, 2)
void dist_stream_kernel(const unsigned short* __restrict__ Xb,
                        const unsigned short* __restrict__ Cb,
                        const float* __restrict__ cnorm,
                        unsigned* __restrict__ list, unsigned* __restrict__ count,
                        unsigned cap)
{
    __shared__ unsigned cbuf[LDSCAP];   // 24 KB
    __shared__ float    cval[LDSCAP];   // 24 KB
    __shared__ unsigned fbuf[FCAP];     // 8 KB
    __shared__ float    wmin[4][64];
    __shared__ float    tokthr[64];
    __shared__ unsigned lcnt, fcnt, gbase;

    const int tid  = threadIdx.x;
    const int lane = tid & 63;
    const int wv   = tid >> 6;
    const int l15  = lane & 15;
    const int quad = lane >> 4;
    const int tok0 = blockIdx.x * 64;
    const int cbase = blockIdx.y * (NCODE / SPLITS_B) + wv * CODES_PER_WAVE;

    if (tid == 0) { lcnt = 0; fcnt = 0; }
    __syncthreads();

    // A fragments: 64 tokens x 256 k, register-resident (128 VGPRs)
    short8 a[4][8];
#pragma unroll
    for (int i = 0; i < 4; ++i) {
        const unsigned short* ap = Xb + (size_t)(tok0 + i * 16 + l15) * DIMD + quad * 8;
#pragma unroll
        for (int ks = 0; ks < 8; ++ks)
            a[i][ks] = *(const short8*)(ap + ks * 32);
    }

    float runv[16], thr[16];
#pragma unroll
    for (int s = 0; s < 16; ++s) { runv[s] = 3.4e38f; thr[s] = 3.4e38f; }

    for (int g = 0; g < NGROUPS; ++g) {
        const int code0 = cbase + g * 16;
        const unsigned short* bp = Cb + (size_t)(code0 + l15) * DIMD + quad * 8;
        short8 b[8];
#pragma unroll
        for (int ks = 0; ks < 8; ++ks) b[ks] = *(const short8*)(bp + ks * 32);
        const float cn = cnorm[code0 + l15];

        floatx4 acc[4];
#pragma unroll
        for (int i = 0; i < 4; ++i) acc[i] = (floatx4){0.f, 0.f, 0.f, 0.f};
#pragma unroll
        for (int ks = 0; ks < 8; ++ks)
#pragma unroll
            for (int i = 0; i < 4; ++i)
                acc[i] = __builtin_amdgcn_mfma_f32_16x16x32_bf16(a[i][ks], b[ks], acc[i], 0, 0, 0);

        // refresh stale threshold every 8 groups (uses runv through g-1)
        if (g != 0 && (g & 7) == 0) {
#pragma unroll
            for (int s = 0; s < 16; ++s) {
                float m = runv[s];
#pragma unroll
                for (int off = 1; off < 16; off <<= 1) m = fminf(m, __shfl_xor(m, off));
                thr[s] = m + MARGIN;
            }
        }

        float d[16];
#pragma unroll
        for (int i = 0; i < 4; ++i)
#pragma unroll
            for (int r = 0; r < 4; ++r) {
                const int s = i * 4 + r;
                const float dd = fmaf(-2.f, acc[i][r], cn);
                d[s] = dd;
                runv[s] = fminf(runv[s], dd);
            }

        if (g == 0) {   // first threshold from group-0 mins (avoids inf-thr flood)
#pragma unroll
            for (int s = 0; s < 16; ++s) {
                float m = runv[s];
#pragma unroll
                for (int off = 1; off < 16; off <<= 1) m = fminf(m, __shfl_xor(m, off));
                thr[s] = m + MARGIN;
            }
        }

        float slack = 3.4e38f;
#pragma unroll
        for (int s = 0; s < 16; ++s) slack = fminf(slack, d[s] - thr[s]);

        if (__any(slack < 0.f)) {   // rare slow path: wave-aggregated LDS append
#pragma unroll
            for (int i = 0; i < 4; ++i)
#pragma unroll
                for (int r = 0; r < 4; ++r) {
                    const int s = i * 4 + r;
                    const bool c = d[s] < thr[s];
                    const unsigned long long m = __ballot(c);
                    if (m == 0ull) continue;
                    if (c) {
                        const int leader = __ffsll((unsigned long long)m) - 1;
                        const unsigned prefix =
                            (unsigned)__popcll(m & ((1ull << lane) - 1ull));
                        unsigned base = 0;
                        if (lane == leader)
                            base = atomicAdd(&lcnt, (unsigned)__popcll(m));
                        base = __shfl(base, leader);
                        const unsigned pos = base + prefix;
                        const unsigned token = tok0 + i * 16 + quad * 4 + r;
                        const unsigned entry = (token << 13) | (unsigned)(code0 + l15);
                        if (pos < LDSCAP) { cbuf[pos] = entry; cval[pos] = d[s]; }
                        else { unsigned gp = atomicAdd(count, 1u); if (gp < cap) list[gp] = entry; }
                    }
                }
        }
    }

    // final per-wave butterfly -> per-token min; combine across 4 waves
#pragma unroll
    for (int s = 0; s < 16; ++s) {
        float m = runv[s];
#pragma unroll
        for (int off = 1; off < 16; off <<= 1) m = fminf(m, __shfl_xor(m, off));
        runv[s] = m;
    }
    if (l15 == 0) {
#pragma unroll
        for (int i = 0; i < 4; ++i)
#pragma unroll
            for (int r = 0; r < 4; ++r)
                wmin[wv][i * 16 + quad * 4 + r] = runv[i * 4 + r];
    }
    __syncthreads();
    if (tid < 64)
        tokthr[tid] = fminf(fminf(wmin[0][tid], wmin[1][tid]),
                            fminf(wmin[2][tid], wmin[3][tid])) + MARGIN;
    __syncthreads();

    // filter raw candidates against block-final min + margin
    const unsigned nn = (lcnt < LDSCAP) ? lcnt : LDSCAP;
    for (unsigned i = tid; i < nn; i += 256) {
        const unsigned e = cbuf[i];
        const unsigned tl = (e >> 13) - (unsigned)tok0;
        if (cval[i] < tokthr[tl]) {
            unsigned p = atomicAdd(&fcnt, 1u);
            if (p < FCAP) fbuf[p] = e;
            else { unsigned gp = atomicAdd(count, 1u); if (gp < cap) list[gp] = e; }
        }
    }
    __syncthreads();

    // flush: one global atomic per block
    const unsigned fn = (fcnt < FCAP) ? fcnt : FCAP;
    if (tid == 0) gbase = atomicAdd(count, fn);
    __syncthreads();
    const unsigned gb = gbase;
    for (unsigned i = tid; i < fn; i += 256) {
        const unsigned p = gb + i;
        if (p < cap) list[p] = fbuf[i];
    }
}

// -------------------------------------------------------------------------
// Kernel 4: exact fp32 rescore. 16-lane groups, 4 candidates per wave.
// Packed (d_bits<<32 | code) atomicMin -> lowest-index tie-break.
// -------------------------------------------------------------------------
__global__ __launch_bounds__(256)
void rescore_kernel(const float* __restrict__ X, const float* __restrict__ C,
                    const float* __restrict__ xnorm, const float* __restrict__ cnorm,
                    const unsigned* __restrict__ list, const unsigned* __restrict__ count,
                    unsigned cap, unsigned long long* __restrict__ fin)
{
    const int lane = threadIdx.x & 63;
    const int g16  = lane & 15;
    const int sub  = lane >> 4;
    const int gid  = ((blockIdx.x * 256 + threadIdx.x) >> 6) * 4 + sub;
    const int ng   = ((gridDim.x * 256) >> 6) * 4;
    unsigned n = *count; if (n > cap) n = cap;

    for (unsigned c = gid; c < n; c += ng) {
        const unsigned e = list[c];
        const unsigned tok = e >> 13, code = e & 8191u;
        const float* xr = &X[(size_t)tok * DIMD];
        const float* cr = &C[(size_t)code * DIMD];
        float dot = 0.f;
#pragma unroll
        for (int r = 0; r < 4; ++r) {
            float4 x4 = *(const float4*)&xr[r * 64 + g16 * 4];
            float4 c4 = *(const float4*)&cr[r * 64 + g16 * 4];
            dot = fmaf(x4.x, c4.x, dot);
            dot = fmaf(x4.y, c4.y, dot);
            dot = fmaf(x4.z, c4.z, dot);
            dot = fmaf(x4.w, c4.w, dot);
        }
#pragma unroll
        for (int d = 1; d < 16; d <<= 1) dot += __shfl_xor(dot, d);
        if (g16 == 0) {
            const float dd = xnorm[tok] + cnorm[code] - 2.f * dot;
            const unsigned long long p =
                ((unsigned long long)__float_as_uint(dd) << 32) | code;
            atomicMin(&fin[tok], p);
        }
    }
}

// -------------------------------------------------------------------------
// Kernel 5: gather winner, straight-through output, loss. One atomic/block.
// -------------------------------------------------------------------------
__global__ __launch_bounds__(256)
void finalize_kernel(const float* __restrict__ X, const float* __restrict__ C,
                     const unsigned long long* __restrict__ fin,
                     float* __restrict__ out)
{
    __shared__ float part[4];
    const int lane = threadIdx.x & 63;
    const int wv   = threadIdx.x >> 6;
    const int t0   = blockIdx.x * 64;

    float local = 0.f;
    for (int it = 0; it < 16; ++it) {
        const int t = t0 + wv * 16 + it;
        const unsigned code = (unsigned)(fin[t] & 0xFFFFFFFFull);
        float4 c4 = *(const float4*)&C[(size_t)code * DIMD + lane * 4];
        float4 x4 = *(const float4*)&X[(size_t)t * DIMD + lane * 4];
        float4 w  = {c4.x - x4.x, c4.y - x4.y, c4.z - x4.z, c4.w - x4.w};
        local += w.x * w.x + w.y * w.y + w.z * w.z + w.w * w.w;
        float4 zq = {x4.x + w.x, x4.y + w.y, x4.z + w.z, x4.w + w.w};
        *(float4*)&out[(size_t)t * DIMD + lane * 4] = zq;
        if (lane == 0) out[NELEM + 1 + t] = (float)code;
    }
#pragma unroll
    for (int off = 1; off < 64; off <<= 1) local += __shfl_xor(local, off);
    if (lane == 0) part[wv] = local;
    __syncthreads();
    if (threadIdx.x == 0) {
        const float s = part[0] + part[1] + part[2] + part[3];
        atomicAdd(&out[NELEM], s * (1.25f / (float)NELEM));
    }
}

// -------------------------------------------------------------------------
extern "C" void kernel_launch(void* const* d_in, const int* in_sizes, int n_in,
                              void* d_out, int out_size, void* d_ws, size_t ws_size,
                              hipStream_t stream)
{
    const float* X = (const float*)d_in[0];
    const float* E = (const float*)d_in[1];
    const float* W = (const float*)d_in[2];
    const float* b = (const float*)d_in[3];
    float* out = (float*)d_out;

    char* w = (char*)d_ws;
    float* C            = (float*)w;           w += (size_t)NCODE * DIMD * 4;
    unsigned short* Xb  = (unsigned short*)w;  w += (size_t)NTOK * DIMD * 2;
    unsigned short* Cb  = (unsigned short*)w;  w += (size_t)NCODE * DIMD * 2;
    float* xnorm        = (float*)w;           w += (size_t)NTOK * 4;
    float* cnorm        = (float*)w;           w += (size_t)NCODE * 4;
    unsigned long long* fin = (unsigned long long*)w; w += (size_t)NTOK * 8;
    unsigned* cnt       = (unsigned*)w;        w += 256;
    unsigned* list      = (unsigned*)w;

    size_t used = (size_t)(w - (char*)d_ws);
    size_t avail = (ws_size > used) ? (ws_size - used) / 4 : 0;
    unsigned cap = (unsigned)((avail > 16777216u) ? 16777216u : avail);

    hipMemsetAsync(cnt, 0, 4, stream);
    hipMemsetAsync(fin, 0xFF, (size_t)NTOK * 8, stream);
    hipMemsetAsync(out + NELEM, 0, 4, stream);

    project_kernel<<<dim3(NCODE / BM, DIMD / BK), 256, 0, stream>>>(E, W, b, C, Cb);
    convx_kernel<<<NTOK / 4, 256, 0, stream>>>(X, xnorm, Xb);
    cnorm_kernel<<<NCODE / 4, 256, 0, stream>>>(C, cnorm);
    dist_stream_kernel<<<dim3(NTOK / 64, SPLITS_B), 256, 0, stream>>>(
        Xb, Cb, cnorm, list, cnt, cap);
    rescore_kernel<<<1024, 256, 0, stream>>>(X, C, xnorm, cnorm, list, cnt, cap, fin);
    finalize_kernel<<<NTOK / 64, 256, 0, stream>>>(X, C, fin, out);
}

// Round 6
// 331.563 us; speedup vs baseline: 40.6056x; 1.0551x over previous
//
#include <hip/hip_runtime.h>

// Problem constants
#define DIMD   256
#define NTOK   16384
#define NCODE  8192
#define NELEM  (NTOK * DIMD)

// fp32 project-GEMM tiling
#define BM 128
#define BK 128
#define BD 32
#define PAD 4
#define LDS_STRIDE (BM + PAD)

// streaming distance kernel
#define SPLITS_B 2                    // grid.y code splits
#define CODES_PER_WAVE (NCODE / SPLITS_B / 4)   // 1024
#define NGROUPS (CODES_PER_WAVE / 16)           // 64
#define MARGIN 0.5f                   // > two-sided worst-case bf16 distance error (~0.4)
#define LDSCAP 6144                   // raw per-block candidate entries
#define FCAP   2048                   // filtered entries

typedef float floatx4 __attribute__((ext_vector_type(4)));
typedef short short8  __attribute__((ext_vector_type(8)));

__device__ __forceinline__ unsigned short f2bf(float f) {
    unsigned u = __float_as_uint(f);
    unsigned r = (u + 0x7FFFu + ((u >> 16) & 1u)) >> 16;
    return (unsigned short)r;
}

// -------------------------------------------------------------------------
// Kernel 1: codebook projection C[k][j] = sum_i E[k][i]*W[j][i] + b[j]
// (fp32) + bf16 copy Cb.
// -------------------------------------------------------------------------
__global__ __launch_bounds__(256, 3)
void project_kernel(const float* __restrict__ E, const float* __restrict__ W,
                    const float* __restrict__ bias, float* __restrict__ C,
                    unsigned short* __restrict__ Cb)
{
    __shared__ float smem[2 * BD * LDS_STRIDE];
    float* As = smem;
    float* Bs = smem + BD * LDS_STRIDE;

    const int tid = threadIdx.x;
    const int tx  = tid & 15;
    const int ty  = tid >> 4;
    const int m0  = blockIdx.x * BM;
    const int j0  = blockIdx.y * BK;

    const int srow = tid >> 3;
    const int scol = (tid & 7) * 4;

    float acc[8][8];
#pragma unroll
    for (int i = 0; i < 8; ++i)
#pragma unroll
        for (int j = 0; j < 8; ++j) acc[i][j] = 0.f;

    for (int dc = 0; dc < DIMD / BD; ++dc) {
        const int d0 = dc * BD;
        __syncthreads();
#pragma unroll
        for (int rr = 0; rr < 4; ++rr) {
            const int r = srow + rr * 32;
            float4 av = *(const float4*)&E[(size_t)(m0 + r) * DIMD + d0 + scol];
            As[(scol + 0) * LDS_STRIDE + r] = av.x;
            As[(scol + 1) * LDS_STRIDE + r] = av.y;
            As[(scol + 2) * LDS_STRIDE + r] = av.z;
            As[(scol + 3) * LDS_STRIDE + r] = av.w;
            float4 bv = *(const float4*)&W[(size_t)(j0 + r) * DIMD + d0 + scol];
            Bs[(scol + 0) * LDS_STRIDE + r] = bv.x;
            Bs[(scol + 1) * LDS_STRIDE + r] = bv.y;
            Bs[(scol + 2) * LDS_STRIDE + r] = bv.z;
            Bs[(scol + 3) * LDS_STRIDE + r] = bv.w;
        }
        __syncthreads();
#pragma unroll 4
        for (int d = 0; d < BD; ++d) {
            float4 a0 = *(float4*)&As[d * LDS_STRIDE + ty * 4];
            float4 a1 = *(float4*)&As[d * LDS_STRIDE + 64 + ty * 4];
            float4 b0 = *(float4*)&Bs[d * LDS_STRIDE + tx * 4];
            float4 b1 = *(float4*)&Bs[d * LDS_STRIDE + 64 + tx * 4];
            float a[8] = {a0.x, a0.y, a0.z, a0.w, a1.x, a1.y, a1.z, a1.w};
            float b[8] = {b0.x, b0.y, b0.z, b0.w, b1.x, b1.y, b1.z, b1.w};
#pragma unroll
            for (int i = 0; i < 8; ++i)
#pragma unroll
                for (int j = 0; j < 8; ++j) acc[i][j] = fmaf(a[i], b[j], acc[i][j]);
        }
    }

    float4 bja = *(const float4*)&bias[j0 + tx * 4];
    float4 bjb = *(const float4*)&bias[j0 + 64 + tx * 4];
#pragma unroll
    for (int i = 0; i < 8; ++i) {
        const int mloc = (i < 4) ? (ty * 4 + i) : (64 + ty * 4 + (i - 4));
        const size_t row = (size_t)(m0 + mloc) * DIMD;
        float o[8] = {acc[i][0] + bja.x, acc[i][1] + bja.y, acc[i][2] + bja.z, acc[i][3] + bja.w,
                      acc[i][4] + bjb.x, acc[i][5] + bjb.y, acc[i][6] + bjb.z, acc[i][7] + bjb.w};
        *(float4*)&C[row + j0 + tx * 4]      = *(float4*)&o[0];
        *(float4*)&C[row + j0 + 64 + tx * 4] = *(float4*)&o[4];
        ushort4 h0 = {f2bf(o[0]), f2bf(o[1]), f2bf(o[2]), f2bf(o[3])};
        ushort4 h1 = {f2bf(o[4]), f2bf(o[5]), f2bf(o[6]), f2bf(o[7])};
        *(ushort4*)&Cb[row + j0 + tx * 4]      = h0;
        *(ushort4*)&Cb[row + j0 + 64 + tx * 4] = h1;
    }
}

// -------------------------------------------------------------------------
// Kernel 2a: X -> xnorm + bf16 Xb
// -------------------------------------------------------------------------
__global__ void convx_kernel(const float* __restrict__ X, float* __restrict__ xnorm,
                             unsigned short* __restrict__ Xb)
{
    const int wave = threadIdx.x >> 6;
    const int lane = threadIdx.x & 63;
    const int row  = blockIdx.x * 4 + wave;
    float4 v = *(const float4*)&X[(size_t)row * DIMD + lane * 4];
    ushort4 h = {f2bf(v.x), f2bf(v.y), f2bf(v.z), f2bf(v.w)};
    *(ushort4*)&Xb[(size_t)row * DIMD + lane * 4] = h;
    float s = v.x * v.x + v.y * v.y + v.z * v.z + v.w * v.w;
#pragma unroll
    for (int off = 1; off < 64; off <<= 1) s += __shfl_xor(s, off);
    if (lane == 0) xnorm[row] = s;
}

__global__ void cnorm_kernel(const float* __restrict__ A, float* __restrict__ out)
{
    const int wave = threadIdx.x >> 6;
    const int lane = threadIdx.x & 63;
    const int row  = blockIdx.x * 4 + wave;
    float4 v = *(const float4*)&A[(size_t)row * DIMD + lane * 4];
    float s = v.x * v.x + v.y * v.y + v.z * v.z + v.w * v.w;
#pragma unroll
    for (int off = 1; off < 64; off <<= 1) s += __shfl_xor(s, off);
    if (lane == 0) out[row] = s;
}

// -------------------------------------------------------------------------
// Kernel 3: barrier-free streaming distance + argmin-candidate kernel.
// Round-6 changes: register double-buffered B prefetch (loads for group g+1
// issued before group g's MFMA chain -> vmcnt stalls hidden); thr[] merged
// into runv (butterflied in place every 8 groups; append test
// dd - runv < MARGIN is a tighter-but-exact superset criterion).
// -------------------------------------------------------------------------
__global__ __launch_bounds__(256, 2)
void dist_stream_kernel(const unsigned short* __restrict__ Xb,
                        const unsigned short* __restrict__ Cb,
                        const float* __restrict__ cnorm,
                        unsigned* __restrict__ list, unsigned* __restrict__ count,
                        unsigned cap)
{
    __shared__ unsigned cbuf[LDSCAP];   // 24 KB
    __shared__ float    cval[LDSCAP];   // 24 KB
    __shared__ unsigned fbuf[FCAP];     // 8 KB
    __shared__ float    wmin[4][64];
    __shared__ float    tokthr[64];
    __shared__ unsigned lcnt, fcnt, gbase;

    const int tid  = threadIdx.x;
    const int lane = tid & 63;
    const int wv   = tid >> 6;
    const int l15  = lane & 15;
    const int quad = lane >> 4;
    const int tok0 = blockIdx.x * 64;
    const int cbase = blockIdx.y * (NCODE / SPLITS_B) + wv * CODES_PER_WAVE;

    if (tid == 0) { lcnt = 0; fcnt = 0; }
    __syncthreads();

    // A fragments: 64 tokens x 256 k, register-resident (128 regs)
    short8 a[4][8];
#pragma unroll
    for (int i = 0; i < 4; ++i) {
        const unsigned short* ap = Xb + (size_t)(tok0 + i * 16 + l15) * DIMD + quad * 8;
#pragma unroll
        for (int ks = 0; ks < 8; ++ks)
            a[i][ks] = *(const short8*)(ap + ks * 32);
    }

    float runv[16];
#pragma unroll
    for (int s = 0; s < 16; ++s) runv[s] = 3.4e38f;

    const unsigned short* bp0 = Cb + (size_t)(cbase + l15) * DIMD + quad * 8;

    // double-buffered B fragments + cnorm
    short8 breg[2][8];
    float  cnr[2];
#pragma unroll
    for (int ks = 0; ks < 8; ++ks) breg[0][ks] = *(const short8*)(bp0 + ks * 32);
    cnr[0] = cnorm[cbase + l15];

    auto group_body = [&](int g, short8 (&bc)[8], short8 (&bn)[8],
                          float cnc, float& cnn) {
        const int code0 = cbase + g * 16;
        // prefetch next group's B + cnorm (consumed one full group later)
        if (g + 1 < NGROUPS) {
            const unsigned short* bpn = bp0 + (size_t)(g + 1) * (16 * DIMD);
#pragma unroll
            for (int ks = 0; ks < 8; ++ks) bn[ks] = *(const short8*)(bpn + ks * 32);
            cnn = cnorm[code0 + 16 + l15];
        }

        floatx4 acc[4];
#pragma unroll
        for (int i = 0; i < 4; ++i) acc[i] = (floatx4){0.f, 0.f, 0.f, 0.f};
#pragma unroll
        for (int ks = 0; ks < 8; ++ks)
#pragma unroll
            for (int i = 0; i < 4; ++i)
                acc[i] = __builtin_amdgcn_mfma_f32_16x16x32_bf16(a[i][ks], bc[ks], acc[i], 0, 0, 0);

        // shared-threshold refresh: butterfly runv in place (prefix <= g-1)
        if (g != 0 && (g & 7) == 0) {
#pragma unroll
            for (int s = 0; s < 16; ++s) {
                float m = runv[s];
#pragma unroll
                for (int off = 1; off < 16; off <<= 1) m = fminf(m, __shfl_xor(m, off));
                runv[s] = m;
            }
        }

        float slack = 3.4e38f;
#pragma unroll
        for (int i = 0; i < 4; ++i)
#pragma unroll
            for (int r = 0; r < 4; ++r) {
                const int s = i * 4 + r;
                const float dd = fmaf(-2.f, acc[i][r], cnc);
                runv[s] = fminf(runv[s], dd);
                slack = fminf(slack, dd - runv[s]);
            }

        if (g == 0) {   // post-butterfly pass avoids inf-threshold flood
#pragma unroll
            for (int s = 0; s < 16; ++s) {
                float m = runv[s];
#pragma unroll
                for (int off = 1; off < 16; off <<= 1) m = fminf(m, __shfl_xor(m, off));
                runv[s] = m;
            }
            slack = 3.4e38f;
#pragma unroll
            for (int i = 0; i < 4; ++i)
#pragma unroll
                for (int r = 0; r < 4; ++r) {
                    const float dd = fmaf(-2.f, acc[i][r], cnc);
                    slack = fminf(slack, dd - runv[i * 4 + r]);
                }
        }

        if (__any(slack < MARGIN)) {   // rare: wave-aggregated LDS append
#pragma unroll
            for (int i = 0; i < 4; ++i)
#pragma unroll
                for (int r = 0; r < 4; ++r) {
                    const int s = i * 4 + r;
                    const float dd = fmaf(-2.f, acc[i][r], cnc);
                    const bool c = (dd - runv[s]) < MARGIN;
                    const unsigned long long m = __ballot(c);
                    if (m == 0ull) continue;
                    if (c) {
                        const int leader = __ffsll(m) - 1;
                        const unsigned prefix =
                            (unsigned)__popcll(m & ((1ull << lane) - 1ull));
                        unsigned base = 0;
                        if (lane == leader)
                            base = atomicAdd(&lcnt, (unsigned)__popcll(m));
                        base = __shfl(base, leader);
                        const unsigned pos = base + prefix;
                        const unsigned token = tok0 + i * 16 + quad * 4 + r;
                        const unsigned entry = (token << 13) | (unsigned)(code0 + l15);
                        if (pos < LDSCAP) { cbuf[pos] = entry; cval[pos] = dd; }
                        else { unsigned gp = atomicAdd(count, 1u); if (gp < cap) list[gp] = entry; }
                    }
                }
        }
    };

    for (int gg = 0; gg < NGROUPS; gg += 2) {
        group_body(gg,     breg[0], breg[1], cnr[0], cnr[1]);
        group_body(gg + 1, breg[1], breg[0], cnr[1], cnr[0]);
    }

    // final per-wave butterfly -> per-token min; combine across 4 waves
#pragma unroll
    for (int s = 0; s < 16; ++s) {
        float m = runv[s];
#pragma unroll
        for (int off = 1; off < 16; off <<= 1) m = fminf(m, __shfl_xor(m, off));
        runv[s] = m;
    }
    if (l15 == 0) {
#pragma unroll
        for (int i = 0; i < 4; ++i)
#pragma unroll
            for (int r = 0; r < 4; ++r)
                wmin[wv][i * 16 + quad * 4 + r] = runv[i * 4 + r];
    }
    __syncthreads();
    if (tid < 64)
        tokthr[tid] = fminf(fminf(wmin[0][tid], wmin[1][tid]),
                            fminf(wmin[2][tid], wmin[3][tid])) + MARGIN;
    __syncthreads();

    // filter raw candidates against block-final min + margin
    const unsigned nn = (lcnt < LDSCAP) ? lcnt : LDSCAP;
    for (unsigned i = tid; i < nn; i += 256) {
        const unsigned e = cbuf[i];
        const unsigned tl = (e >> 13) - (unsigned)tok0;
        if (cval[i] < tokthr[tl]) {
            unsigned p = atomicAdd(&fcnt, 1u);
            if (p < FCAP) fbuf[p] = e;
            else { unsigned gp = atomicAdd(count, 1u); if (gp < cap) list[gp] = e; }
        }
    }
    __syncthreads();

    // flush: one global atomic per block
    const unsigned fn = (fcnt < FCAP) ? fcnt : FCAP;
    if (tid == 0) gbase = atomicAdd(count, fn);
    __syncthreads();
    const unsigned gb = gbase;
    for (unsigned i = tid; i < fn; i += 256) {
        const unsigned p = gb + i;
        if (p < cap) list[p] = fbuf[i];
    }
}

// -------------------------------------------------------------------------
// Kernel 4: exact fp32 rescore. 16-lane groups, 4 candidates per wave.
// Packed (d_bits<<32 | code) atomicMin -> lowest-index tie-break.
// -------------------------------------------------------------------------
__global__ __launch_bounds__(256)
void rescore_kernel(const float* __restrict__ X, const float* __restrict__ C,
                    const float* __restrict__ xnorm, const float* __restrict__ cnorm,
                    const unsigned* __restrict__ list, const unsigned* __restrict__ count,
                    unsigned cap, unsigned long long* __restrict__ fin)
{
    const int lane = threadIdx.x & 63;
    const int g16  = lane & 15;
    const int sub  = lane >> 4;
    const int gid  = ((blockIdx.x * 256 + threadIdx.x) >> 6) * 4 + sub;
    const int ng   = ((gridDim.x * 256) >> 6) * 4;
    unsigned n = *count; if (n > cap) n = cap;

    for (unsigned c = gid; c < n; c += ng) {
        const unsigned e = list[c];
        const unsigned tok = e >> 13, code = e & 8191u;
        const float* xr = &X[(size_t)tok * DIMD];
        const float* cr = &C[(size_t)code * DIMD];
        float dot = 0.f;
#pragma unroll
        for (int r = 0; r < 4; ++r) {
            float4 x4 = *(const float4*)&xr[r * 64 + g16 * 4];
            float4 c4 = *(const float4*)&cr[r * 64 + g16 * 4];
            dot = fmaf(x4.x, c4.x, dot);
            dot = fmaf(x4.y, c4.y, dot);
            dot = fmaf(x4.z, c4.z, dot);
            dot = fmaf(x4.w, c4.w, dot);
        }
#pragma unroll
        for (int d = 1; d < 16; d <<= 1) dot += __shfl_xor(dot, d);
        if (g16 == 0) {
            const float dd = xnorm[tok] + cnorm[code] - 2.f * dot;
            const unsigned long long p =
                ((unsigned long long)__float_as_uint(dd) << 32) | code;
            atomicMin(&fin[tok], p);
        }
    }
}

// -------------------------------------------------------------------------
// Kernel 5: gather winner, straight-through output, loss. One atomic/block.
// -------------------------------------------------------------------------
__global__ __launch_bounds__(256)
void finalize_kernel(const float* __restrict__ X, const float* __restrict__ C,
                     const unsigned long long* __restrict__ fin,
                     float* __restrict__ out)
{
    __shared__ float part[4];
    const int lane = threadIdx.x & 63;
    const int wv   = threadIdx.x >> 6;
    const int t0   = blockIdx.x * 64;

    float local = 0.f;
    for (int it = 0; it < 16; ++it) {
        const int t = t0 + wv * 16 + it;
        const unsigned code = (unsigned)(fin[t] & 0xFFFFFFFFull);
        float4 c4 = *(const float4*)&C[(size_t)code * DIMD + lane * 4];
        float4 x4 = *(const float4*)&X[(size_t)t * DIMD + lane * 4];
        float4 w  = {c4.x - x4.x, c4.y - x4.y, c4.z - x4.z, c4.w - x4.w};
        local += w.x * w.x + w.y * w.y + w.z * w.z + w.w * w.w;
        float4 zq = {x4.x + w.x, x4.y + w.y, x4.z + w.z, x4.w + w.w};
        *(float4*)&out[(size_t)t * DIMD + lane * 4] = zq;
        if (lane == 0) out[NELEM + 1 + t] = (float)code;
    }
#pragma unroll
    for (int off = 1; off < 64; off <<= 1) local += __shfl_xor(local, off);
    if (lane == 0) part[wv] = local;
    __syncthreads();
    if (threadIdx.x == 0) {
        const float s = part[0] + part[1] + part[2] + part[3];
        atomicAdd(&out[NELEM], s * (1.25f / (float)NELEM));
    }
}

// -------------------------------------------------------------------------
extern "C" void kernel_launch(void* const* d_in, const int* in_sizes, int n_in,
                              void* d_out, int out_size, void* d_ws, size_t ws_size,
                              hipStream_t stream)
{
    const float* X = (const float*)d_in[0];
    const float* E = (const float*)d_in[1];
    const float* W = (const float*)d_in[2];
    const float* b = (const float*)d_in[3];
    float* out = (float*)d_out;

    char* w = (char*)d_ws;
    float* C            = (float*)w;           w += (size_t)NCODE * DIMD * 4;
    unsigned short* Xb  = (unsigned short*)w;  w += (size_t)NTOK * DIMD * 2;
    unsigned short* Cb  = (unsigned short*)w;  w += (size_t)NCODE * DIMD * 2;
    float* xnorm        = (float*)w;           w += (size_t)NTOK * 4;
    float* cnorm        = (float*)w;           w += (size_t)NCODE * 4;
    unsigned long long* fin = (unsigned long long*)w; w += (size_t)NTOK * 8;
    unsigned* cnt       = (unsigned*)w;        w += 256;
    unsigned* list      = (unsigned*)w;

    size_t used = (size_t)(w - (char*)d_ws);
    size_t avail = (ws_size > used) ? (ws_size - used) / 4 : 0;
    unsigned cap = (unsigned)((avail > 16777216u) ? 16777216u : avail);

    hipMemsetAsync(cnt, 0, 4, stream);
    hipMemsetAsync(fin, 0xFF, (size_t)NTOK * 8, stream);
    hipMemsetAsync(out + NELEM, 0, 4, stream);

    project_kernel<<<dim3(NCODE / BM, DIMD / BK), 256, 0, stream>>>(E, W, b, C, Cb);
    convx_kernel<<<NTOK / 4, 256, 0, stream>>>(X, xnorm, Xb);
    cnorm_kernel<<<NCODE / 4, 256, 0, stream>>>(C, cnorm);
    dist_stream_kernel<<<dim3(NTOK / 64, SPLITS_B), 256, 0, stream>>>(
        Xb, Cb, cnorm, list, cnt, cap);
    rescore_kernel<<<1024, 256, 0, stream>>>(X, C, xnorm, cnorm, list, cnt, cap, fin);
    finalize_kernel<<<NTOK / 64, 256, 0, stream>>>(X, C, fin, out);
}